// Round 4
// baseline (324.817 us; speedup 1.0000x reference)
//
#include <hip/hip_runtime.h>
#include <stdint.h>

// MFMA fragment types (gfx950)
typedef __attribute__((ext_vector_type(8))) short short8;  // 8 bf16 = 4 VGPRs
typedef __attribute__((ext_vector_type(4))) float f32x4;   // 4 fp32 acc / vec load

static_assert(sizeof(short8) == 16, "frag size");

__device__ __forceinline__ uint16_t f2bf(float f) {
  uint32_t u = __builtin_bit_cast(uint32_t, f);
  u += 0x7fffu + ((u >> 16) & 1u);
  return (uint16_t)(u >> 16);
}

__device__ __forceinline__ short8 pack_bf16x8(f32x4 lo, f32x4 hi) {
  union { uint32_t u[4]; short8 s; } z;
  z.u[0] = (uint32_t)f2bf(lo.x) | ((uint32_t)f2bf(lo.y) << 16);
  z.u[1] = (uint32_t)f2bf(lo.z) | ((uint32_t)f2bf(lo.w) << 16);
  z.u[2] = (uint32_t)f2bf(hi.x) | ((uint32_t)f2bf(hi.y) << 16);
  z.u[3] = (uint32_t)f2bf(hi.z) | ((uint32_t)f2bf(hi.w) << 16);
  return z.s;
}

__device__ __forceinline__ void gload_lds16(const void* g, void* lds_wave_base) {
  // async global->LDS, 16B/lane; LDS dst = wave-uniform base + lane*16
  __builtin_amdgcn_global_load_lds(
      (__attribute__((address_space(1))) void*)(void*)(g),
      (__attribute__((address_space(3))) void*)(lds_wave_base),
      16, 0, 0);
}

// ---------------------------------------------------------------------------
// quant: dwT[o][i] = ternary(weight[i][o]) in {-1,0,+1} bf16, LINEAR layout
// (R4: support reads B fragments directly from global; no swizzle needed).
// ---------------------------------------------------------------------------
__global__ __launch_bounds__(256) void quant_kernel(const float* __restrict__ w,
                                                    uint16_t* __restrict__ dwT) {
  const int o = blockIdx.x, i = threadIdx.x;
  const float v = w[i * 256 + o];
  const float t = (v > 0.01f) ? 1.0f : ((v < -0.01f) ? -1.0f : 0.0f);
  dwT[o * 256 + i] = f2bf(t);
}

// ---------------------------------------------------------------------------
// support (SINGLE-PASS K=256): spt[o][g] = bf16(0.01 * sum_i x[g][i]*tern[i][o])
// R4: only x staged in LDS (32 KB -> 4-5 blocks/CU, was 64 KB / 2 blocks);
// dwT (128 KB, L1/L2-resident) read directly as B fragments.
// Tile [64 g][64 o]; grid 1024 = 256 g-tiles x 4 o-tiles.
// spt stored LINEAR [256 o][16384 g] (main reads it directly).
// ---------------------------------------------------------------------------
#define SB_A 0       // [64 g][256 i] bf16 swizzled, 32768 B (reused in epilogue)

__global__ __launch_bounds__(256) void support_kernel(const float* __restrict__ x,
                                                      const uint16_t* __restrict__ dwT,
                                                      uint16_t* __restrict__ spt) {
  __shared__ __align__(16) unsigned char smem[32768];
  const int t = threadIdx.x, lane = t & 63, w = t >> 6;
  const int r = lane & 15, q = lane >> 4;
  const int g0 = (blockIdx.x & 255) * 64;
  const int o0 = (blockIdx.x >> 8) * 64;

  // stage A: x [64 g][256 i] fp32 -> bf16, packed b128 swizzled writes
#pragma unroll
  for (int j = 0; j < 8; ++j) {
    const int id = j * 256 + t;              // 64 rows x 32 chunks = 2048 ids
    const int row = id >> 5, c = id & 31;
    const float* p = x + (size_t)(g0 + row) * 256 + c * 8;
    const f32x4 v0 = *(const f32x4*)p;
    const f32x4 v1 = *(const f32x4*)(p + 4);
    uint4 u;
    u.x = (uint32_t)f2bf(v0.x) | ((uint32_t)f2bf(v0.y) << 16);
    u.y = (uint32_t)f2bf(v0.z) | ((uint32_t)f2bf(v0.w) << 16);
    u.z = (uint32_t)f2bf(v1.x) | ((uint32_t)f2bf(v1.y) << 16);
    u.w = (uint32_t)f2bf(v1.z) | ((uint32_t)f2bf(v1.w) << 16);
    *(uint4*)(smem + SB_A + row * 512 + ((c ^ (row & 7)) << 4)) = u;
  }
  __syncthreads();

  f32x4 acc[4] = {};
#pragma unroll
  for (int h = 0; h < 8; ++h) {              // K=256 in 8 steps of 32
    short8 av, bv[4];
    const int pc = (((h * 4 + q) ^ (r & 7)) << 4);
    av = *(const short8*)(smem + SB_A + (16 * w + r) * 512 + pc);
#pragma unroll
    for (int ni = 0; ni < 4; ++ni)           // B direct from global (L2-hit)
      bv[ni] = *(const short8*)(dwT + (size_t)(o0 + 16 * ni + r) * 256 + h * 32 + q * 8);
#pragma unroll
    for (int ni = 0; ni < 4; ++ni)
      acc[ni] = __builtin_amdgcn_mfma_f32_16x16x32_bf16(av, bv[ni], acc[ni], 0, 0, 0);
  }
  __syncthreads();   // all waves' LDS reads done before transpose overwrite

  // epilogue: transpose buffer [64 o][64 g] bf16 (8 KB, reuses SB_A region).
  // LDS writes swizzled (conflict-free); copy-out un-swizzles -> spt LINEAR.
#pragma unroll
  for (int ni = 0; ni < 4; ++ni) {
    const int ol = 16 * ni + r;              // C col = o
#pragma unroll
    for (int reg = 0; reg < 4; ++reg) {
      const int gl = 16 * w + 4 * q + reg;   // C row = g
      const int gsw = gl ^ ((ol & 7) << 3);  // LDS-local swizzle only
      *(uint16_t*)(smem + (ol * 64 + gsw) * 2) = f2bf(acc[ni][reg] * 0.01f);
    }
  }
  __syncthreads();
#pragma unroll
  for (int it = 0; it < 2; ++it) {
    const int id = it * 256 + t, row = id >> 3, cc = id & 7;
    const uint4 u = *(const uint4*)(smem + (row * 64 + ((cc ^ (row & 7)) * 8)) * 2);
    *(uint4*)(spt + (size_t)(o0 + row) * 16384 + g0 + cc * 8) = u;
  }
}

// ---------------------------------------------------------------------------
// main v5 (A-only LDS via raw-fp32 DMA, B direct from L2, 16 waves/CU):
//   out = relu(adj @ support + bias)
// R3 lesson: compiler collapses register pipelines (VGPR=56) -> only
// global_load_lds staging structurally stays in flight. R2 lesson: staging
// BOTH operands + 2 barriers/step serializes everything (6000 cyc/step).
// Here: A (adj, the HBM stream) staged as RAW FP32 by DMA (no reg round-trip,
// no ds_write, conversion at consumption); B (spt, 1 MB/XCD, L2-resident)
// read directly as fragments. 512-thread blocks, wave=[16n][64o] (acc 16
// VGPRs), LDS = 2 x 32 KB A-dbuf -> 2 blocks/CU = 16 waves/CU. BK=256 ->
// 8 barriers total; each DMA (32 KB) covered by ~8 chunks of compute plus
// the other block's phase offset.
// A-LDS swizzle (m201 both-sides pattern): LDS[row][c16] = global chunk
// (c&~7)|((c&7)^(row&7)); reader fetches chunk (h*8+2q)^(r&7) -> uniform
// bank spread for f32x4 reads, DMA source stays 64B-coalesced.
// ---------------------------------------------------------------------------
__global__ __launch_bounds__(512, 4) void gcn_main_kernel(const float* __restrict__ adj,
                                                          const uint16_t* __restrict__ spt,
                                                          const float* __restrict__ bias,
                                                          float* __restrict__ out) {
  __shared__ __align__(16) unsigned char smem[65536];  // 2 x 32 KB A buffers
  const int t = threadIdx.x, lane = t & 63, wv = t >> 6;
  const int r = lane & 15, q = lane >> 4;
  const int nh = wv >> 2;                    // n half (0/1)
  const int oq = wv & 3;                     // o quarter
  const int bb = blockIdx.x & 7;             // batch -> XCD affinity (spt[bb] L2-resident)
  const int n0 = (blockIdx.x >> 3) * 32;     // n-tile (64 tiles x 8 bb = 512 blocks)
  const float* adjb = adj + ((size_t)bb * 2048 + n0) * 2048;
  const uint16_t* sptb = spt + (size_t)bb * 2048;

  // ---- A-DMA indexing: 32 rows x 64 chunks(16B) per 256-K step, 4 rounds.
  // Round j, wave w stages row (j*8+w); lane l covers chunk c=l with
  // inverse-swizzled global source -> LDS ends up [row][c]=(global swz).
  const int dRow = t >> 6;                   // = wv (row base for j=0)
  const int dC = lane;                       // chunk 0..63
  const int dCs = (dC & ~7) | ((dC & 7) ^ (dRow & 7));  // NOTE row changes with j!
  (void)dCs;

#define A_DMA(K0, BUF)                                                         \
  do {                                                                         \
    _Pragma("unroll") for (int j = 0; j < 4; ++j) {                            \
      const int row_ = j * 8 + wv;                                             \
      const int cs_ = (dC & ~7) | ((dC & 7) ^ (row_ & 7));                     \
      gload_lds16(adjb + (size_t)row_ * 2048 + (K0) + cs_ * 4,                 \
                  smem + (BUF) + (size_t)(j * 512 + wv * 64) * 16);            \
    }                                                                          \
  } while (0)

  f32x4 acc[4] = {};

  // prologue: stage step 0 into buf0
  A_DMA(0, 0u);
  __syncthreads();

  const int aRowOff = (nh * 16 + r) * 1024;  // byte offset of my A row in buf
  const int rr = r & 7;

  for (int kt = 0; kt < 8; ++kt) {
    const unsigned cur = (kt & 1) ? 32768u : 0u;
    const unsigned nxt = (kt & 1) ? 0u : 32768u;
    if (kt < 7) A_DMA((kt + 1) * 256, nxt);  // in flight under this step's compute

#pragma unroll
    for (int h = 0; h < 8; ++h) {            // 8 chunks of K=32
      const int ch0 = h * 8 + ((2 * q) ^ rr);
      const int ch1 = h * 8 + ((2 * q + 1) ^ rr);
      const f32x4 a0 = *(const f32x4*)(smem + cur + aRowOff + ch0 * 16);
      const f32x4 a1 = *(const f32x4*)(smem + cur + aRowOff + ch1 * 16);
      const short8 av = pack_bf16x8(a0, a1);
      const int kk = kt * 256 + h * 32 + q * 8;
      short8 bv[4];
#pragma unroll
      for (int ni = 0; ni < 4; ++ni)
        bv[ni] = *(const short8*)(sptb + (size_t)(oq * 64 + 16 * ni + r) * 16384 + kk);
#pragma unroll
      for (int ni = 0; ni < 4; ++ni)
        acc[ni] = __builtin_amdgcn_mfma_f32_16x16x32_bf16(av, bv[ni], acc[ni], 0, 0, 0);
    }
    __syncthreads();                         // drains DMA(kt+1); buf swap safe
  }

  // epilogue: +bias, relu, fp32 store
#pragma unroll
  for (int ni = 0; ni < 4; ++ni) {
    const int o = oq * 64 + 16 * ni + r;     // C col = N = o
    const float bs = bias[o];
#pragma unroll
    for (int reg = 0; reg < 4; ++reg) {
      const int n = n0 + nh * 16 + 4 * q + reg;  // C row = M = n
      out[((size_t)bb * 2048 + n) * 256 + o] = fmaxf(acc[ni][reg] + bs, 0.0f);
    }
  }
#undef A_DMA
}

// ---------------------------------------------------------------------------
extern "C" void kernel_launch(void* const* d_in, const int* in_sizes, int n_in,
                              void* d_out, int out_size, void* d_ws, size_t ws_size,
                              hipStream_t stream) {
  const float* x      = (const float*)d_in[0];  // [8,2048,256]
  const float* adj    = (const float*)d_in[1];  // [8,2048,2048]
  const float* weight = (const float*)d_in[2];  // [256,256]
  const float* bias   = (const float*)d_in[3];  // [256]
  float* out = (float*)d_out;                   // [8,2048,256]

  uint16_t* dwT = (uint16_t*)d_ws;                          // 128 KB
  uint16_t* spt = (uint16_t*)((char*)d_ws + 131072);        // 8 MB

  hipLaunchKernelGGL(quant_kernel,    dim3(256),  dim3(256), 0, stream, weight, dwT);
  hipLaunchKernelGGL(support_kernel,  dim3(1024), dim3(256), 0, stream, x, dwT, spt);
  hipLaunchKernelGGL(gcn_main_kernel, dim3(512),  dim3(512), 0, stream, adj, spt, bias, out);
}

// Round 5
// 235.048 us; speedup vs baseline: 1.3819x; 1.3819x over previous
//
#include <hip/hip_runtime.h>
#include <stdint.h>

// MFMA fragment types (gfx950)
typedef __attribute__((ext_vector_type(8))) short short8;  // 8 bf16 = 4 VGPRs
typedef __attribute__((ext_vector_type(4))) float f32x4;   // 4 fp32 acc / vec load

static_assert(sizeof(short8) == 16, "frag size");

__device__ __forceinline__ uint16_t f2bf(float f) {
  uint32_t u = __builtin_bit_cast(uint32_t, f);
  u += 0x7fffu + ((u >> 16) & 1u);
  return (uint16_t)(u >> 16);
}

__device__ __forceinline__ void gload_lds16(const void* g, void* lds_wave_base) {
  // async global->LDS, 16B/lane; LDS dst = wave-uniform base + lane*16
  __builtin_amdgcn_global_load_lds(
      (__attribute__((address_space(1))) void*)(void*)(g),
      (__attribute__((address_space(3))) void*)(lds_wave_base),
      16, 0, 0);
}

// Swizzle convention (all bf16 staging): within each 64-elem K-group, 16B
// chunk c of row r is stored at chunk c ^ (r&7) (XOR touches bits 0-2 only,
// composing transparently with any BK). DMA stages tiles verbatim; fragment
// reads at chunk (h*4+q)^(r&7) are conflict-free ds_read_b128.
// (R0-proven: SQ_LDS_BANK_CONFLICT == 0.)

// ---------------------------------------------------------------------------
// quant: dwT[o][i] = ternary(weight[i][o]) in {-1,0,+1} bf16, swizzled.
// ---------------------------------------------------------------------------
__global__ __launch_bounds__(256) void quant_kernel(const float* __restrict__ w,
                                                    uint16_t* __restrict__ dwT) {
  const int o = blockIdx.x, i = threadIdx.x;
  const float v = w[i * 256 + o];
  const float t = (v > 0.01f) ? 1.0f : ((v < -0.01f) ? -1.0f : 0.0f);
  dwT[o * 256 + (i ^ ((o & 7) << 3))] = f2bf(t);
}

// ---------------------------------------------------------------------------
// support (SINGLE-PASS K=256): spt[o][g] = bf16(0.01 * sum_i x[g][i]*tern[i][o])
// R0-proven version: tile [64 g][64 o], full K staged once (64 KB LDS,
// 2 blocks/CU). Grid 1024 = 256 g-tiles x 4 o-tiles. spt stored SWIZZLED
// (main's B-DMA stages it verbatim).
// ---------------------------------------------------------------------------
#define SB_A 0       // [64 g][256 i] bf16 swizzled, 32768 B (reused in epilogue)
#define SB_B 32768   // [64 o][256 i] bf16 swizzled, 32768 B

__global__ __launch_bounds__(256) void support_kernel(const float* __restrict__ x,
                                                      const uint16_t* __restrict__ dwT,
                                                      uint16_t* __restrict__ spt) {
  __shared__ __align__(16) unsigned char smem[65536];
  const int t = threadIdx.x, lane = t & 63, w = t >> 6;
  const int r = lane & 15, q = lane >> 4;
  const int g0 = (blockIdx.x & 255) * 64;
  const int o0 = (blockIdx.x >> 8) * 64;

  // stage A: x [64 g][256 i] fp32 -> bf16, packed b128 swizzled writes
#pragma unroll
  for (int j = 0; j < 8; ++j) {
    const int id = j * 256 + t;              // 64 rows x 32 chunks = 2048 ids
    const int row = id >> 5, c = id & 31;
    const float* p = x + (size_t)(g0 + row) * 256 + c * 8;
    const f32x4 v0 = *(const f32x4*)p;
    const f32x4 v1 = *(const f32x4*)(p + 4);
    uint4 u;
    u.x = (uint32_t)f2bf(v0.x) | ((uint32_t)f2bf(v0.y) << 16);
    u.y = (uint32_t)f2bf(v0.z) | ((uint32_t)f2bf(v0.w) << 16);
    u.z = (uint32_t)f2bf(v1.x) | ((uint32_t)f2bf(v1.y) << 16);
    u.w = (uint32_t)f2bf(v1.z) | ((uint32_t)f2bf(v1.w) << 16);
    *(uint4*)(smem + SB_A + row * 512 + ((c ^ (row & 7)) << 4)) = u;
  }
  // stage B: dwT rows [o0,o0+64) full K, verbatim DMA (pre-swizzled)
#pragma unroll
  for (int j = 0; j < 8; ++j) {
    const int id = j * 256 + t, row = id >> 5, c = id & 31;
    gload_lds16(dwT + (size_t)(o0 + row) * 256 + c * 8,
                smem + SB_B + (size_t)(j * 256 + w * 64) * 16);
  }
  __syncthreads();

  f32x4 acc[4] = {};
#pragma unroll
  for (int h = 0; h < 8; ++h) {              // K=256 in 8 steps of 32
    short8 av, bv[4];
    const int pc = (((h * 4 + q) ^ (r & 7)) << 4);
    av = *(const short8*)(smem + SB_A + (16 * w + r) * 512 + pc);
#pragma unroll
    for (int ni = 0; ni < 4; ++ni)
      bv[ni] = *(const short8*)(smem + SB_B + (16 * ni + r) * 512 + pc);
#pragma unroll
    for (int ni = 0; ni < 4; ++ni)
      acc[ni] = __builtin_amdgcn_mfma_f32_16x16x32_bf16(av, bv[ni], acc[ni], 0, 0, 0);
  }
  __syncthreads();   // all waves' LDS reads done before transpose overwrite

  // epilogue: transpose buffer [64 o][64 g] bf16 (8 KB, reuses SB_A region);
  // the XOR here embeds the GLOBAL spt swizzle (chunk c^(o&7) per 64-g group).
#pragma unroll
  for (int ni = 0; ni < 4; ++ni) {
    const int ol = 16 * ni + r;              // C col = o
#pragma unroll
    for (int reg = 0; reg < 4; ++reg) {
      const int gl = 16 * w + 4 * q + reg;   // C row = g
      const int gsw = gl ^ ((ol & 7) << 3);  // global col swizzle
      *(uint16_t*)(smem + (ol * 64 + gsw) * 2) = f2bf(acc[ni][reg] * 0.01f);
    }
  }
  __syncthreads();
  // copy out: 64 rows x 8 chunks of 16 B, coalesced dwordx4
#pragma unroll
  for (int it = 0; it < 2; ++it) {
    const int id = it * 256 + t, row = id >> 3, cc = id & 7;
    const uint4 u = *(const uint4*)(smem + (row * 64 + cc * 8) * 2);
    *(uint4*)(spt + (size_t)(o0 + row) * 16384 + g0 + cc * 8) = u;
  }
}

// ---------------------------------------------------------------------------
// main v6 (R0 datapath, 512 threads = 16 waves/CU): out = relu(adj@spt + bias)
// Single-variable change vs the 79.7us R0 kernel: 256 -> 512 threads/block.
// Tile [32 n][256 o], BK=128, 16 steps, 2 barriers/step, LDS 72 KB ->
// 2 blocks/CU. 8 waves/block, wave = [16 n][64 o] (nh = wv>>2, oq = wv&3),
// acc = 16 VGPR. Per-thread staging halves (A: 1 uint4, B: 8 DMA).
// Rationale (R2/R4 counters): everything idle at 19% occupancy; in-block
// pipelining (R1/R2) was neutral; direct-global operands (R3/R4) collapse.
// The untested axis is wave TLP: 16 waves/CU lets block X's compute cover
// block Y's barrier-drain.
// ---------------------------------------------------------------------------
#define MB_A 0       // [32][128] bf16 swizzled, 8192 B
#define MB_B 8192    // [256][128] bf16 (spt pre-swizzled), 65536 B

__global__ __launch_bounds__(512, 4) void gcn_main_kernel(const float* __restrict__ adj,
                                                          const uint16_t* __restrict__ spt,
                                                          const float* __restrict__ bias,
                                                          float* __restrict__ out) {
  __shared__ __align__(16) unsigned char smem[73728];
  const int t = threadIdx.x, lane = t & 63, wv = t >> 6;
  const int r = lane & 15, q = lane >> 4;
  const int nh = wv >> 2;                    // n-half (0/1)
  const int oq = wv & 3;                     // o-quarter
  const int bb = blockIdx.x & 7;             // batch -> XCD affinity (spt[bb] L2-resident)
  const int n0 = (blockIdx.x >> 3) * 32;     // n-tile
  const float* adjb = adj + ((size_t)bb * 2048 + n0) * 2048;
  const uint16_t* sptb = spt + (size_t)bb * 2048;

  // A staging: [32 n][128 m] = 512 chunks of 16B(bf16) <- 32 B fp32/thread
  const int aRow = t >> 4, aC = t & 15;
  const float* aP = adjb + (size_t)aRow * 2048 + aC * 8;
  const unsigned aOff = aRow * 256 + ((aC ^ (aRow & 7)) << 4);

  f32x4 acc[4] = {};

  for (int kt = 0; kt < 16; ++kt) {
    const int k0 = kt * 128;
    // B-DMA first (async, stays in flight under A's load latency)
#pragma unroll
    for (int j = 0; j < 8; ++j) {
      const int id = j * 512 + t, row = id >> 4, c = id & 15;
      gload_lds16(sptb + (size_t)row * 16384 + k0 + c * 8,
                  smem + MB_B + (size_t)(j * 512 + wv * 64) * 16);
    }
    // A: 32 B fp32 -> 16 B bf16, swizzled b128 write
    {
      const f32x4 v0 = *(const f32x4*)(aP + k0);
      const f32x4 v1 = *(const f32x4*)(aP + k0 + 4);
      uint4 u;
      u.x = (uint32_t)f2bf(v0.x) | ((uint32_t)f2bf(v0.y) << 16);
      u.y = (uint32_t)f2bf(v0.z) | ((uint32_t)f2bf(v0.w) << 16);
      u.z = (uint32_t)f2bf(v1.x) | ((uint32_t)f2bf(v1.y) << 16);
      u.w = (uint32_t)f2bf(v1.z) | ((uint32_t)f2bf(v1.w) << 16);
      *(uint4*)(smem + MB_A + aOff) = u;
    }
    __syncthreads();                         // drains DMA + ds_write

#pragma unroll
    for (int h = 0; h < 4; ++h) {            // 4 k-slices of 32
      const int pc = (((h * 4 + q) ^ (r & 7)) << 4);
      const short8 av = *(const short8*)(smem + MB_A + (nh * 16 + r) * 256 + pc);
      short8 bv[4];
#pragma unroll
      for (int ni = 0; ni < 4; ++ni)
        bv[ni] = *(const short8*)(smem + MB_B + (oq * 64 + 16 * ni + r) * 256 + pc);
#pragma unroll
      for (int ni = 0; ni < 4; ++ni)
        acc[ni] = __builtin_amdgcn_mfma_f32_16x16x32_bf16(av, bv[ni], acc[ni], 0, 0, 0);
    }
    __syncthreads();                         // LDS reads done before next stage
  }

  // epilogue: +bias, relu, fp32 store
#pragma unroll
  for (int ni = 0; ni < 4; ++ni) {
    const int o = oq * 64 + 16 * ni + r;     // C col = N = o
    const float bs = bias[o];
#pragma unroll
    for (int reg = 0; reg < 4; ++reg) {
      const int n = n0 + nh * 16 + 4 * q + reg;  // C row = M = n
      out[((size_t)bb * 2048 + n) * 256 + o] = fmaxf(acc[ni][reg] + bs, 0.0f);
    }
  }
}

// ---------------------------------------------------------------------------
extern "C" void kernel_launch(void* const* d_in, const int* in_sizes, int n_in,
                              void* d_out, int out_size, void* d_ws, size_t ws_size,
                              hipStream_t stream) {
  const float* x      = (const float*)d_in[0];  // [8,2048,256]
  const float* adj    = (const float*)d_in[1];  // [8,2048,2048]
  const float* weight = (const float*)d_in[2];  // [256,256]
  const float* bias   = (const float*)d_in[3];  // [256]
  float* out = (float*)d_out;                   // [8,2048,256]

  uint16_t* dwT = (uint16_t*)d_ws;                          // 128 KB
  uint16_t* spt = (uint16_t*)((char*)d_ws + 131072);        // 8 MB

  hipLaunchKernelGGL(quant_kernel,    dim3(256),  dim3(256), 0, stream, weight, dwT);
  hipLaunchKernelGGL(support_kernel,  dim3(1024), dim3(256), 0, stream, x, dwT, spt);
  hipLaunchKernelGGL(gcn_main_kernel, dim3(512),  dim3(512), 0, stream, adj, spt, bias, out);
}